// Round 8
// baseline (1417.945 us; speedup 1.0000x reference)
//
#include <hip/hip_runtime.h>
#include <hip/hip_bf16.h>

// ---------------------------------------------------------------------------
// ArmNet forward. Round 8: transform GEMM epilogue rewritten to LDS-staged
// fully-coalesced line writes (round-7 counters showed 209MB writes / 386MB
// fetch vs ~117/~102 ideal: partial-line bf16 stores caused RFO + L3 thrash).
// Rest unchanged from round 7.
// ---------------------------------------------------------------------------

constexpr int kN1 = 393216;   // encoder nodes
constexpr int kE1 = 327680;   // encoder edges
constexpr int kN2 = 917504;   // decoder nodes
constexpr int kE2 = 851968;   // decoder edges
constexpr int kM  = 65536;    // B*PERIOD (transform GEMM rows)
constexpr int kK  = 384;      // transform K
constexpr int kN  = 896;      // transform N (14*64)

typedef __attribute__((ext_vector_type(8))) short bf16x8;
typedef __attribute__((ext_vector_type(4))) float f32x4;

__device__ inline float2 bf2_unpack(unsigned u) {
    union { unsigned i; float f; } a, b;
    a.i = u << 16;           // element 2j   (low half)
    b.i = u & 0xffff0000u;   // element 2j+1 (high half)
    return make_float2(a.f, b.f);
}

__device__ inline ushort f2bf(float f) {   // RNE f32 -> bf16 (finite inputs)
    union { float f; unsigned u; } x; x.f = f;
    unsigned r = x.u + 0x7fffu + ((x.u >> 16) & 1u);
    return (ushort)(r >> 16);
}

__device__ inline void pack8(ushort* d, float4 u, float4 v) {
    bf16x8 p;
    p[0] = (short)f2bf(u.x); p[1] = (short)f2bf(u.y);
    p[2] = (short)f2bf(u.z); p[3] = (short)f2bf(u.w);
    p[4] = (short)f2bf(v.x); p[5] = (short)f2bf(v.y);
    p[6] = (short)f2bf(v.z); p[7] = (short)f2bf(v.w);
    *(bf16x8*)d = p;
}

// ---------------- spatial edge MLP (small layers: enc1, dec3) --------------
template<int IN, int EA, int OUT, int TPB, int ITER>
__global__ __launch_bounds__(TPB)
void spatial_edge_kernel(const float* __restrict__ x,
                         const int* __restrict__ ei, int E,
                         const float* __restrict__ ea,
                         const float* __restrict__ Wl,
                         const float* __restrict__ bl,
                         float* __restrict__ out)
{
    constexpr int Z  = 2 * IN + EA;
    constexpr int Zp = (Z % 2 == 0) ? Z + 1 : Z;   // odd stride: conflict-free
    constexpr int EPB = TPB / OUT;
    static_assert(TPB % OUT == 0, "TPB % OUT");
    __shared__ float sW[OUT * Zp];
    __shared__ float sB[OUT];
    for (int i = threadIdx.x; i < OUT * Z; i += TPB)
        sW[(i / Z) * Zp + (i % Z)] = Wl[i];
    for (int i = threadIdx.x; i < OUT; i += TPB) sB[i] = bl[i];
    __syncthreads();

    const int le = threadIdx.x / OUT;
    const int c  = threadIdx.x % OUT;
    const float* __restrict__ w = &sW[c * Zp];
    const int base = blockIdx.x * EPB * ITER;

    #pragma unroll 1
    for (int it = 0; it < ITER; ++it) {
        const int e = base + it * EPB + le;
        if (e >= E) break;
        const int src = ei[e];
        const int dst = ei[E + e];
        float acc = sB[c];
        if constexpr (IN % 4 == 0) {
            const float4* __restrict__ xd4 = (const float4*)&x[(long)dst * IN];
            const float4* __restrict__ xs4 = (const float4*)&x[(long)src * IN];
            #pragma unroll
            for (int q = 0; q < IN / 4; ++q) {
                const float4 v = xd4[q];
                acc = fmaf(w[4*q+0], v.x, acc); acc = fmaf(w[4*q+1], v.y, acc);
                acc = fmaf(w[4*q+2], v.z, acc); acc = fmaf(w[4*q+3], v.w, acc);
            }
            #pragma unroll
            for (int q = 0; q < IN / 4; ++q) {
                const float4 v = xs4[q];
                acc = fmaf(w[IN+4*q+0], v.x, acc); acc = fmaf(w[IN+4*q+1], v.y, acc);
                acc = fmaf(w[IN+4*q+2], v.z, acc); acc = fmaf(w[IN+4*q+3], v.w, acc);
            }
        } else {
            const float* __restrict__ xd = &x[(long)dst * IN];
            const float* __restrict__ xs = &x[(long)src * IN];
            #pragma unroll
            for (int j = 0; j < IN; ++j) acc = fmaf(w[j], xd[j], acc);
            #pragma unroll
            for (int j = 0; j < IN; ++j) acc = fmaf(w[IN + j], xs[j], acc);
        }
        const float* __restrict__ eav = &ea[(long)e * EA];
        #pragma unroll
        for (int j = 0; j < EA; ++j) acc = fmaf(w[2 * IN + j], eav[j], acc);
        acc = acc > 0.f ? acc : 0.01f * acc;     // leaky_relu(0.01)
        atomicAdd(&out[(long)dst * OUT + c], acc);
    }
}

// ---------------- spatial edge layer as fused gather-MFMA-scatter GEMM -----
template<int IN, int EA, int OUT, int KSTEPS>
__global__ __launch_bounds__(256)
void spatial_gemm_kernel(const float* __restrict__ x,
                         const int* __restrict__ ei, int E,
                         const float* __restrict__ ea,
                         const float* __restrict__ Wl,
                         const float* __restrict__ bl,
                         float* __restrict__ out)
{
    constexpr int Z    = 2 * IN + EA;
    constexpr int KPAD = KSTEPS * 32;
    static_assert(Z <= KPAD, "K pad");
    static_assert(IN % 8 == 0, "IN vec");
    constexpr int LDA = KPAD + 8;      // multiple of 8 ushorts (16B aligned rows)
    constexpr int MT  = 128;
    constexpr int NF  = OUT / 16;
    __shared__ ushort sA[MT * LDA];
    __shared__ ushort sB[OUT * LDA];
    __shared__ float  sBias[OUT];
    __shared__ int    sDst[MT];

    const int tid = threadIdx.x;
    const int e0  = blockIdx.x * MT;

    // stage B (zero-padded k)
    for (int i = tid; i < OUT * KPAD; i += 256) {
        const int ch = i / KPAD, j = i % KPAD;
        sB[ch * LDA + j] = (j < Z) ? f2bf(Wl[ch * Z + j]) : (ushort)0;
    }
    if (tid < OUT) sBias[tid] = bl[tid];

    // stage A: 2 threads per edge row (sh=0: dst half, sh=1: src half + ea + pad)
    {
        const int r  = tid >> 1, sh = tid & 1;
        const int e  = e0 + r;
        const int node = sh ? ei[e] : ei[E + e];
        const float4* __restrict__ xr = (const float4*)&x[(long)node * IN];
        ushort* d = &sA[r * LDA + sh * IN];
        #pragma unroll
        for (int q = 0; q < IN / 4; q += 2)
            pack8(d + q * 4, xr[q], xr[q + 1]);
        if (sh == 0) {
            sDst[r] = node;
        } else {
            const float* __restrict__ eav = &ea[(long)e * EA];
            #pragma unroll
            for (int j = 0; j < EA; ++j) d[IN + j] = f2bf(eav[j]);  // abs 2*IN+j
            #pragma unroll
            for (int j = Z; j < KPAD; ++j) sA[r * LDA + j] = 0;
        }
    }
    __syncthreads();

    const int lane = tid & 63, wid = tid >> 6;
    const int g = lane >> 4, rsel = lane & 15;
    f32x4 acc[2][NF] = {};
    #pragma unroll
    for (int ks = 0; ks < KSTEPS; ++ks) {
        bf16x8 a_[2], b_[NF];
        #pragma unroll
        for (int m = 0; m < 2; ++m)
            a_[m] = *(const bf16x8*)&sA[(wid*32 + m*16 + rsel) * LDA + ks*32 + g*8];
        #pragma unroll
        for (int n = 0; n < NF; ++n)
            b_[n] = *(const bf16x8*)&sB[(n*16 + rsel) * LDA + ks*32 + g*8];
        #pragma unroll
        for (int m = 0; m < 2; ++m)
            #pragma unroll
            for (int n = 0; n < NF; ++n)
                acc[m][n] = __builtin_amdgcn_mfma_f32_16x16x32_bf16(
                    a_[m], b_[n], acc[m][n], 0, 0, 0);
    }

    // epilogue: row = wid*32 + m*16 + g*4 + rr ; col = n*16 + rsel
    #pragma unroll
    for (int m = 0; m < 2; ++m) {
        #pragma unroll
        for (int rr = 0; rr < 4; ++rr) {
            const int row = wid*32 + m*16 + g*4 + rr;
            const long dst = sDst[row];
            #pragma unroll
            for (int n = 0; n < NF; ++n) {
                const int col = n*16 + rsel;
                float v = acc[m][n][rr] + sBias[col];
                v = v > 0.f ? v : 0.01f * v;
                atomicAdd(&out[dst * OUT + col], v);
            }
        }
    }
}

// ---------------- generic upsample (residual linear) -----------------------
template<int IN, int OUT, int ITER>
__global__ __launch_bounds__(256)
void upsample_kernel(const float* __restrict__ x, int N,
                     const float* __restrict__ Wu,
                     const float* __restrict__ bu,
                     float* __restrict__ out)
{
    constexpr int INp = (IN % 2 == 0) ? IN + 1 : IN;
    __shared__ float sW[OUT * INp];
    __shared__ float sB[OUT];
    for (int i = threadIdx.x; i < OUT * IN; i += 256)
        sW[(i / IN) * INp + (i % IN)] = Wu[i];
    for (int i = threadIdx.x; i < OUT; i += 256) sB[i] = bu[i];
    __syncthreads();

    const int total = N * OUT;
    #pragma unroll 1
    for (int it = 0; it < ITER; ++it) {
        const int idx = (blockIdx.x * ITER + it) * 256 + threadIdx.x;
        if (idx >= total) break;
        const int n = idx / OUT, c = idx % OUT;
        const float* __restrict__ w = &sW[c * INp];
        float acc = sB[c];
        if constexpr (IN % 4 == 0) {
            const float4* __restrict__ xv4 = (const float4*)&x[(long)n * IN];
            #pragma unroll
            for (int q = 0; q < IN / 4; ++q) {
                const float4 v = xv4[q];
                acc = fmaf(w[4*q+0], v.x, acc); acc = fmaf(w[4*q+1], v.y, acc);
                acc = fmaf(w[4*q+2], v.z, acc); acc = fmaf(w[4*q+3], v.w, acc);
            }
        } else {
            const float* __restrict__ xv = &x[(long)n * IN];
            #pragma unroll
            for (int j = 0; j < IN; ++j) acc = fmaf(w[j], xv[j], acc);
        }
        out[idx] = acc;
    }
}

template<int ITER>
__global__ __launch_bounds__(256)
void dec1_upsample_kernel(const __hip_bfloat16* __restrict__ zt,
                          const float* __restrict__ lo,
                          const float* __restrict__ up,
                          const float* __restrict__ Wu,  // [32, 66]
                          const float* __restrict__ bu,
                          float* __restrict__ out, int N)
{
    constexpr int IN = 66, INp = 67, OUT = 32;
    __shared__ float sW[OUT * INp];
    __shared__ float sB[OUT];
    for (int i = threadIdx.x; i < OUT * IN; i += 256)
        sW[(i / IN) * INp + (i % IN)] = Wu[i];
    if (threadIdx.x < OUT) sB[threadIdx.x] = bu[threadIdx.x];
    __syncthreads();

    const int total = N * OUT;
    #pragma unroll 1
    for (int it = 0; it < ITER; ++it) {
        const int idx = (blockIdx.x * ITER + it) * 256 + threadIdx.x;
        if (idx >= total) break;
        const int n = idx >> 5, c = idx & 31;
        const float* __restrict__ w = &sW[c * INp];
        const uint4* __restrict__ zn4 = (const uint4*)&zt[(long)n * 64];
        float acc = sB[c];
        #pragma unroll
        for (int q = 0; q < 8; ++q) {
            const uint4 u = zn4[q];
            float2 v;
            v = bf2_unpack(u.x); acc = fmaf(w[8*q+0], v.x, acc); acc = fmaf(w[8*q+1], v.y, acc);
            v = bf2_unpack(u.y); acc = fmaf(w[8*q+2], v.x, acc); acc = fmaf(w[8*q+3], v.y, acc);
            v = bf2_unpack(u.z); acc = fmaf(w[8*q+4], v.x, acc); acc = fmaf(w[8*q+5], v.y, acc);
            v = bf2_unpack(u.w); acc = fmaf(w[8*q+6], v.x, acc); acc = fmaf(w[8*q+7], v.y, acc);
        }
        acc = fmaf(w[64], lo[n], acc);
        acc = fmaf(w[65], up[n], acc);
        out[idx] = acc;
    }
}

// ---------------- temporal (dim 64) as fused gather-MFMA-scatter GEMM ------
__global__ __launch_bounds__(256)
void temporal_gemm_kernel(const float* __restrict__ x,
                          const int* __restrict__ ei, int E,
                          const float* __restrict__ Wt,  // [64,128]
                          const float* __restrict__ bt,
                          float* __restrict__ s, float* __restrict__ cnt)
{
    constexpr int MT = 128, LDA = 136, LDB = 136;
    __shared__ ushort sA[MT * LDA];     // 34816 B
    __shared__ ushort sB[64 * LDB];     // 17408 B
    __shared__ float  sBias[64];
    __shared__ int    sDst[MT];

    const int tid = threadIdx.x;
    const int e0  = blockIdx.x * MT;

    // stage B (Wt) + bias
    for (int i = tid; i < 64 * 32; i += 256) {
        const int ch = i >> 5, q = i & 31;
        const float4 v = *(const float4*)&Wt[ch * 128 + q * 4];
        ushort* d = &sB[ch * LDB + q * 4];
        d[0] = f2bf(v.x); d[1] = f2bf(v.y); d[2] = f2bf(v.z); d[3] = f2bf(v.w);
    }
    if (tid < 64) sBias[tid] = bt[tid];

    // stage A: 2 threads per edge row (sh=0: dst half, sh=1: src half)
    {
        const int r  = tid >> 1, sh = tid & 1;
        const int e  = e0 + r;
        const int node = sh ? ei[e] : ei[E + e];
        const float4* __restrict__ xr = (const float4*)&x[(long)node * 64];
        ushort* d = &sA[r * LDA + sh * 64];
        #pragma unroll
        for (int q = 0; q < 16; q += 2)
            pack8(d + q * 4, xr[q], xr[q + 1]);
        if (sh == 0) {
            sDst[r] = node;
            atomicAdd(&cnt[node], 1.f);
        }
    }
    __syncthreads();

    // MFMA: wave wid owns edge rows [wid*32, wid*32+32)
    const int lane = tid & 63, wid = tid >> 6;
    const int g = lane >> 4, rsel = lane & 15;
    f32x4 acc[2][4] = {};
    #pragma unroll
    for (int ks = 0; ks < 4; ++ks) {
        bf16x8 a_[2], b_[4];
        #pragma unroll
        for (int m = 0; m < 2; ++m)
            a_[m] = *(const bf16x8*)&sA[(wid*32 + m*16 + rsel) * LDA + ks*32 + g*8];
        #pragma unroll
        for (int n = 0; n < 4; ++n)
            b_[n] = *(const bf16x8*)&sB[(n*16 + rsel) * LDB + ks*32 + g*8];
        #pragma unroll
        for (int m = 0; m < 2; ++m)
            #pragma unroll
            for (int n = 0; n < 4; ++n)
                acc[m][n] = __builtin_amdgcn_mfma_f32_16x16x32_bf16(
                    a_[m], b_[n], acc[m][n], 0, 0, 0);
    }

    #pragma unroll
    for (int m = 0; m < 2; ++m) {
        #pragma unroll
        for (int rr = 0; rr < 4; ++rr) {
            const int row = wid*32 + m*16 + g*4 + rr;
            const long dst = sDst[row];
            #pragma unroll
            for (int n = 0; n < 4; ++n) {
                const int col = n*16 + rsel;
                const float v = fmaxf(acc[m][n][rr] + sBias[col], 0.f);
                atomicAdd(&s[dst * 64 + col], v);
            }
        }
    }
}

// ---------------- decoder layer-1 as fused gather-MFMA-scatter GEMM --------
__global__ __launch_bounds__(256)
void dec1_gemm_kernel(const __hip_bfloat16* __restrict__ zt,
                      const float* __restrict__ lo, const float* __restrict__ up,
                      const int* __restrict__ ei, int E,
                      const float* __restrict__ ea,   // [E,6]
                      const float* __restrict__ Wl,   // [32,138]
                      const float* __restrict__ bl,
                      float* __restrict__ out)        // [N2,32]
{
    constexpr int MT = 128, LDA = 168, LDB = 168;
    __shared__ ushort sA[MT * LDA];     // 43008 B
    __shared__ ushort sB[32 * LDB];     // 10752 B
    __shared__ float  sBias[32];
    __shared__ int    sDst[MT];

    const int tid = threadIdx.x;
    const int e0  = blockIdx.x * MT;

    for (int i = tid; i < 32 * 160; i += 256) {
        const int ch = i / 160, j = i % 160;
        sB[ch * LDB + j] = (j < 138) ? f2bf(Wl[ch * 138 + j]) : (ushort)0;
    }
    if (tid < 32) sBias[tid] = bl[tid];

    {
        const int r  = tid >> 1, sh = tid & 1;
        const int e  = e0 + r;
        const int node = sh ? ei[e] : ei[E + e];
        ushort* d = &sA[r * LDA + sh * 66];
        uint* d32 = (uint*)d;                     // 4B-aligned
        const uint4* __restrict__ zr = (const uint4*)&zt[(long)node * 64];
        #pragma unroll
        for (int q = 0; q < 8; ++q) {
            const uint4 u = zr[q];
            d32[4*q+0] = u.x; d32[4*q+1] = u.y; d32[4*q+2] = u.z; d32[4*q+3] = u.w;
        }
        d[64] = f2bf(lo[node]);
        d[65] = f2bf(up[node]);
        if (sh) {
            const float* __restrict__ eav = &ea[(long)e * 6];
            #pragma unroll
            for (int j = 0; j < 6; ++j) d[66 + j] = f2bf(eav[j]);
            #pragma unroll
            for (int j = 72; j < 94; ++j) d[j] = 0;   // k 138..159
        } else {
            sDst[r] = node;
        }
    }
    __syncthreads();

    const int lane = tid & 63, wid = tid >> 6;
    const int g = lane >> 4, rsel = lane & 15;
    f32x4 acc[2][2] = {};
    #pragma unroll
    for (int ks = 0; ks < 5; ++ks) {
        bf16x8 a_[2], b_[2];
        #pragma unroll
        for (int m = 0; m < 2; ++m)
            a_[m] = *(const bf16x8*)&sA[(wid*32 + m*16 + rsel) * LDA + ks*32 + g*8];
        #pragma unroll
        for (int n = 0; n < 2; ++n)
            b_[n] = *(const bf16x8*)&sB[(n*16 + rsel) * LDB + ks*32 + g*8];
        #pragma unroll
        for (int m = 0; m < 2; ++m)
            #pragma unroll
            for (int n = 0; n < 2; ++n)
                acc[m][n] = __builtin_amdgcn_mfma_f32_16x16x32_bf16(
                    a_[m], b_[n], acc[m][n], 0, 0, 0);
    }

    #pragma unroll
    for (int m = 0; m < 2; ++m) {
        #pragma unroll
        for (int rr = 0; rr < 4; ++rr) {
            const int row = wid*32 + m*16 + g*4 + rr;
            const long dst = sDst[row];
            #pragma unroll
            for (int n = 0; n < 2; ++n) {
                const int col = n*16 + rsel;
                float v = acc[m][n][rr] + sBias[col];
                v = v > 0.f ? v : 0.01f * v;
                atomicAdd(&out[dst * 32 + col], v);
            }
        }
    }
}

// ---------------- temporal combine / dim-1 temporal ------------------------
__global__ void temporal_combine64_kernel(const float* __restrict__ s,
                                          const float* __restrict__ cnt,
                                          const float* __restrict__ x,
                                          float* __restrict__ z, int N)
{
    int idx = blockIdx.x * blockDim.x + threadIdx.x;
    if (idx >= N * 64) return;
    const int n = idx >> 6;
    z[idx] = s[idx] / fmaxf(cnt[n], 1.f) + x[idx];
}

__global__ void temporal_edge1_kernel(const float* __restrict__ x,
                                      const int* __restrict__ ei, int E,
                                      const float* __restrict__ Wt,
                                      const float* __restrict__ bt,
                                      float* __restrict__ s, float* __restrict__ cnt)
{
    int e = blockIdx.x * blockDim.x + threadIdx.x;
    if (e >= E) return;
    const int src = ei[e];
    const int dst = ei[E + e];
    float m = Wt[0] * x[dst] + Wt[1] * x[src] + bt[0];
    m = fmaxf(m, 0.f);
    atomicAdd(&s[dst], m);
    atomicAdd(&cnt[dst], 1.f);
}

// ---------------- transform GEMM (bf16 MFMA, coalesced epilogue) -----------
__global__ __launch_bounds__(256)
void gemm_mfma_tanh_kernel(const float* __restrict__ A,
                           const float* __restrict__ W,
                           const float* __restrict__ bias,
                           __hip_bfloat16* __restrict__ out)
{
    constexpr int BM = 128, LDP = 40;   // ushort pitch: 80B rows, 2-way banks
    constexpr int LDC = 144;            // epilogue staging pitch (288B rows)
    __shared__ ushort smem[2 * BM * LDP];   // 20480 B; sA | sB, reused as sC
    ushort* sA = smem;
    ushort* sB = smem + BM * LDP;
    const int tid  = threadIdx.x;
    const int lane = tid & 63;
    const int wid  = tid >> 6;
    const int wr = wid >> 1, wc = wid & 1;
    const long bm = (long)blockIdx.y * BM;
    const long bn = (long)blockIdx.x * BM;

    const int sr = tid >> 1;      // 0..127: staged tile row
    const int sh = tid & 1;       // 0/1: which 16-element k-half
    const float* __restrict__ gA = &A[(bm + sr) * kK + sh * 16];
    const float* __restrict__ gB = &W[(bn + sr) * kK + sh * 16];
    ushort* dA = &sA[sr * LDP + sh * 16];
    ushort* dB = &sB[sr * LDP + sh * 16];

    f32x4 acc[4][4] = {};
    const int g    = lane >> 4;   // k-group (8 bf16 each)
    const int rsel = lane & 15;

    for (int k0 = 0; k0 < kK; k0 += 32) {
        const float4 a0 = *(const float4*)(gA + k0 + 0);
        const float4 a1 = *(const float4*)(gA + k0 + 4);
        const float4 a2 = *(const float4*)(gA + k0 + 8);
        const float4 a3 = *(const float4*)(gA + k0 + 12);
        const float4 b0 = *(const float4*)(gB + k0 + 0);
        const float4 b1 = *(const float4*)(gB + k0 + 4);
        const float4 b2 = *(const float4*)(gB + k0 + 8);
        const float4 b3 = *(const float4*)(gB + k0 + 12);
        __syncthreads();                      // previous tile fully consumed
        pack8(dA, a0, a1); pack8(dA + 8, a2, a3);
        pack8(dB, b0, b1); pack8(dB + 8, b2, b3);
        __syncthreads();

        bf16x8 af[4], bfm[4];
        #pragma unroll
        for (int m = 0; m < 4; ++m)
            af[m] = *(const bf16x8*)&sA[(wr * 64 + m * 16 + rsel) * LDP + g * 8];
        #pragma unroll
        for (int n = 0; n < 4; ++n)
            bfm[n] = *(const bf16x8*)&sB[(wc * 64 + n * 16 + rsel) * LDP + g * 8];
        #pragma unroll
        for (int m = 0; m < 4; ++m)
            #pragma unroll
            for (int n = 0; n < 4; ++n)
                acc[m][n] = __builtin_amdgcn_mfma_f32_16x16x32_bf16(
                    af[m], bfm[n], acc[m][n], 0, 0, 0);
    }

    // bias per lane-owned columns
    float bias_r[4];
    #pragma unroll
    for (int n = 0; n < 4; ++n)
        bias_r[n] = bias[bn + wc * 64 + n * 16 + rsel];

    // Coalesced epilogue: two passes of 64 rows via LDS staging (reuses smem).
    // sC[row][col] (pitch 144 ushorts) then full 256B-per-row line writes.
    ushort* sC = smem;
    __syncthreads();
    #pragma unroll
    for (int p = 0; p < 2; ++p) {
        if (wr == p) {
            #pragma unroll
            for (int m = 0; m < 4; ++m)
                #pragma unroll
                for (int n = 0; n < 4; ++n)
                    #pragma unroll
                    for (int r = 0; r < 4; ++r) {
                        const int row = m * 16 + g * 4 + r;
                        const int col = wc * 64 + n * 16 + rsel;
                        sC[row * LDC + col] = f2bf(tanhf(acc[m][n][r] + bias_r[n]));
                    }
        }
        __syncthreads();
        {
            const int row = tid >> 2, ch = tid & 3;     // 64 rows x 4 chunks of 64B
            const uint4* __restrict__ srcp = (const uint4*)&sC[row * LDC + ch * 32];
            uint4* __restrict__ dstp = (uint4*)&out[(bm + p * 64 + row) * kN + bn + ch * 32];
            #pragma unroll
            for (int q = 0; q < 4; ++q) dstp[q] = srcp[q];
        }
        __syncthreads();
    }
}

// ---------------- final: tanh(temporal) -> affine to joint range -----------
__global__ void final_kernel(const float* __restrict__ s,
                             const float* __restrict__ cnt,
                             const float* __restrict__ d3,
                             const float* __restrict__ lo,
                             const float* __restrict__ up,
                             float* __restrict__ out, int N)
{
    int i = blockIdx.x * blockDim.x + threadIdx.x;
    if (i >= N) return;
    const float t = s[i] / fmaxf(cnt[i], 1.f) + d3[i];
    const float o = tanhf(t);
    out[i] = lo[i] + (up[i] - lo[i]) * (o + 1.f) * 0.5f;
}

// ---------------------------------------------------------------------------
extern "C" void kernel_launch(void* const* d_in, const int* in_sizes, int n_in,
                              void* d_out, int out_size, void* d_ws, size_t ws_size,
                              hipStream_t stream)
{
    const float* x     = (const float*)d_in[0];
    const int*   ei1   = (const int*)  d_in[1];
    const float* ea1   = (const float*)d_in[2];
    const int*   tei1  = (const int*)  d_in[3];
    const float* lower = (const float*)d_in[4];
    const float* upper = (const float*)d_in[5];
    const int*   ei2   = (const int*)  d_in[6];
    const float* ea2   = (const float*)d_in[7];
    const int*   tei2  = (const int*)  d_in[8];
    const float* We1_l = (const float*)d_in[9];  const float* be1_l = (const float*)d_in[10];
    const float* We1_u = (const float*)d_in[11]; const float* be1_u = (const float*)d_in[12];
    const float* We2_l = (const float*)d_in[13]; const float* be2_l = (const float*)d_in[14];
    const float* We2_u = (const float*)d_in[15]; const float* be2_u = (const float*)d_in[16];
    const float* We3_l = (const float*)d_in[17]; const float* be3_l = (const float*)d_in[18];
    const float* We3_u = (const float*)d_in[19]; const float* be3_u = (const float*)d_in[20];
    const float* Wt1   = (const float*)d_in[21]; const float* bt1   = (const float*)d_in[22];
    const float* W_tr  = (const float*)d_in[23]; const float* b_tr  = (const float*)d_in[24];
    const float* Wd1_l = (const float*)d_in[25]; const float* bd1_l = (const float*)d_in[26];
    const float* Wd1_u = (const float*)d_in[27]; const float* bd1_u = (const float*)d_in[28];
    const float* Wd2_l = (const float*)d_in[29]; const float* bd2_l = (const float*)d_in[30];
    const float* Wd2_u = (const float*)d_in[31]; const float* bd2_u = (const float*)d_in[32];
    const float* Wd3_l = (const float*)d_in[33]; const float* bd3_l = (const float*)d_in[34];
    const float* Wd3_u = (const float*)d_in[35]; const float* bd3_u = (const float*)d_in[36];
    const float* Wt2   = (const float*)d_in[37]; const float* bt2   = (const float*)d_in[38];

    // workspace layout (bytes):
    //   bufA: 117,440,512   (holds h1/h3/zt(bf16)/d2)
    //   bufB: 117,440,512   (holds h2/s1/z/d1/d3)
    //   bufC:   7,340,032   (holds cnt1 | s2+cnt2)
    char* ws = (char*)d_ws;
    float* bufA = (float*)ws;
    float* bufB = (float*)(ws + 117440512);
    float* bufC = (float*)(ws + 234881024);
    __hip_bfloat16* zt = (__hip_bfloat16*)bufA;

    const int TPB = 256;
    auto cdiv = [](long a, long b) { return (int)((a + b - 1) / b); };

    // ---- encoder spatial 1: x[6] -> h1[16]  (h1 = bufA)
    upsample_kernel<6, 16, 8><<<cdiv((long)kN1 * 16, 2048), TPB, 0, stream>>>(
        x, kN1, We1_u, be1_u, bufA);
    spatial_edge_kernel<6, 3, 16, 256, 4><<<cdiv(kE1, 64), TPB, 0, stream>>>(
        x, ei1, kE1, ea1, We1_l, be1_l, bufA);

    // ---- encoder spatial 2: h1[16] -> h2[32]  (h2 = bufB)
    upsample_kernel<16, 32, 8><<<cdiv((long)kN1 * 32, 2048), TPB, 0, stream>>>(
        bufA, kN1, We2_u, be2_u, bufB);
    spatial_gemm_kernel<16, 3, 32, 2><<<kE1 / 128, TPB, 0, stream>>>(
        bufA, ei1, kE1, ea1, We2_l, be2_l, bufB);

    // ---- encoder spatial 3: h2[32] -> h3[64]  (h3 = bufA)
    upsample_kernel<32, 64, 8><<<cdiv((long)kN1 * 64, 2048), TPB, 0, stream>>>(
        bufB, kN1, We3_u, be3_u, bufA);
    spatial_gemm_kernel<32, 3, 64, 3><<<kE1 / 128, TPB, 0, stream>>>(
        bufB, ei1, kE1, ea1, We3_l, be3_l, bufA);

    // ---- encoder temporal (dim 64): s1 = bufB, cnt1 = bufC, z in-place bufB
    hipMemsetAsync(bufB, 0, (size_t)kN1 * 64 * sizeof(float), stream);
    hipMemsetAsync(bufC, 0, (size_t)kN1 * sizeof(float), stream);
    temporal_gemm_kernel<<<kN1 / 128, 256, 0, stream>>>(
        bufA, tei1, kN1, Wt1, bt1, bufB, bufC);
    temporal_combine64_kernel<<<cdiv((long)kN1 * 64, TPB), TPB, 0, stream>>>(
        bufB, bufC, bufA, bufB, kN1);

    // ---- transform GEMM: z(bufB [65536,384] f32) @ W_tr^T -> tanh -> zt bf16
    {
        dim3 grid(kN / 128, kM / 128);
        gemm_mfma_tanh_kernel<<<grid, 256, 0, stream>>>(bufB, W_tr, b_tr, zt);
    }

    // ---- decoder spatial 1: x2[66] (virtual) -> d1[32]  (d1 = bufB)
    dec1_upsample_kernel<8><<<cdiv((long)kN2 * 32, 2048), TPB, 0, stream>>>(
        zt, lower, upper, Wd1_u, bd1_u, bufB, kN2);
    dec1_gemm_kernel<<<kE2 / 128, 256, 0, stream>>>(
        zt, lower, upper, ei2, kE2, ea2, Wd1_l, bd1_l, bufB);

    // ---- decoder spatial 2: d1[32] -> d2[16]  (d2 = bufA as f32)
    float* d2 = (float*)bufA;
    upsample_kernel<32, 16, 8><<<cdiv((long)kN2 * 16, 2048), TPB, 0, stream>>>(
        bufB, kN2, Wd2_u, bd2_u, d2);
    spatial_gemm_kernel<32, 6, 16, 3><<<kE2 / 128, TPB, 0, stream>>>(
        bufB, ei2, kE2, ea2, Wd2_l, bd2_l, d2);

    // ---- decoder spatial 3: d2[16] -> d3[1]  (d3 = bufB)
    float* d3 = bufB;
    upsample_kernel<16, 1, 8><<<cdiv(kN2, 2048), TPB, 0, stream>>>(
        d2, kN2, Wd3_u, bd3_u, d3);
    spatial_edge_kernel<16, 6, 1, 256, 1><<<cdiv(kE2, 256), TPB, 0, stream>>>(
        d2, ei2, kE2, ea2, Wd3_l, bd3_l, d3);

    // ---- decoder temporal (dim 1) + final affine
    hipMemsetAsync(bufC, 0, (size_t)2 * kN2 * sizeof(float), stream);
    temporal_edge1_kernel<<<cdiv(kN2, TPB), TPB, 0, stream>>>(
        d3, tei2, kN2, Wt2, bt2, bufC, bufC + kN2);
    final_kernel<<<cdiv(kN2, TPB), TPB, 0, stream>>>(
        bufC, bufC + kN2, d3, lower, upper, (float*)d_out, kN2);
}

// Round 11
// 1391.906 us; speedup vs baseline: 1.0187x; 1.0187x over previous
//
#include <hip/hip_runtime.h>
#include <hip/hip_bf16.h>

// ---------------------------------------------------------------------------
// ArmNet forward. Round 9 changes (resubmitted; rounds 9-10 benches were
// infra acquisition timeouts, kernel never ran):
// transform GEMM gets (1) XCD-chunked block swizzle so the 7 blocks sharing
// an A-panel land on one XCD's L2 (round-8 FETCH was 381MB vs 102MB ideal =
// ~7x A re-fetch across XCDs), (2) hardware cvt for f32->bf16 staging (manual
// 4-op RNE was ~half the VALU), (3) epilogue LDS pitch 152 (288B-row pitch
// was an 8-way bank conflict). Rest unchanged.
// ---------------------------------------------------------------------------

constexpr int kN1 = 393216;   // encoder nodes
constexpr int kE1 = 327680;   // encoder edges
constexpr int kN2 = 917504;   // decoder nodes
constexpr int kE2 = 851968;   // decoder edges
constexpr int kM  = 65536;    // B*PERIOD (transform GEMM rows)
constexpr int kK  = 384;      // transform K
constexpr int kN  = 896;      // transform N (14*64)

typedef __attribute__((ext_vector_type(8))) short bf16x8;
typedef __attribute__((ext_vector_type(4))) float f32x4;

__device__ inline float2 bf2_unpack(unsigned u) {
    union { unsigned i; float f; } a, b;
    a.i = u << 16;           // element 2j   (low half)
    b.i = u & 0xffff0000u;   // element 2j+1 (high half)
    return make_float2(a.f, b.f);
}

__device__ inline ushort f2bf(float f) {   // RNE via HW cvt (compiler lowers)
    __hip_bfloat16 h = __float2bfloat16(f);
    union { __hip_bfloat16 h; ushort u; } c; c.h = h; return c.u;
}

__device__ inline void pack8(ushort* d, float4 u, float4 v) {
    bf16x8 p;
    p[0] = (short)f2bf(u.x); p[1] = (short)f2bf(u.y);
    p[2] = (short)f2bf(u.z); p[3] = (short)f2bf(u.w);
    p[4] = (short)f2bf(v.x); p[5] = (short)f2bf(v.y);
    p[6] = (short)f2bf(v.z); p[7] = (short)f2bf(v.w);
    *(bf16x8*)d = p;
}

// ---------------- spatial edge MLP (small layers: enc1, dec3) --------------
template<int IN, int EA, int OUT, int TPB, int ITER>
__global__ __launch_bounds__(TPB)
void spatial_edge_kernel(const float* __restrict__ x,
                         const int* __restrict__ ei, int E,
                         const float* __restrict__ ea,
                         const float* __restrict__ Wl,
                         const float* __restrict__ bl,
                         float* __restrict__ out)
{
    constexpr int Z  = 2 * IN + EA;
    constexpr int Zp = (Z % 2 == 0) ? Z + 1 : Z;   // odd stride: conflict-free
    constexpr int EPB = TPB / OUT;
    static_assert(TPB % OUT == 0, "TPB % OUT");
    __shared__ float sW[OUT * Zp];
    __shared__ float sB[OUT];
    for (int i = threadIdx.x; i < OUT * Z; i += TPB)
        sW[(i / Z) * Zp + (i % Z)] = Wl[i];
    for (int i = threadIdx.x; i < OUT; i += TPB) sB[i] = bl[i];
    __syncthreads();

    const int le = threadIdx.x / OUT;
    const int c  = threadIdx.x % OUT;
    const float* __restrict__ w = &sW[c * Zp];
    const int base = blockIdx.x * EPB * ITER;

    #pragma unroll 1
    for (int it = 0; it < ITER; ++it) {
        const int e = base + it * EPB + le;
        if (e >= E) break;
        const int src = ei[e];
        const int dst = ei[E + e];
        float acc = sB[c];
        if constexpr (IN % 4 == 0) {
            const float4* __restrict__ xd4 = (const float4*)&x[(long)dst * IN];
            const float4* __restrict__ xs4 = (const float4*)&x[(long)src * IN];
            #pragma unroll
            for (int q = 0; q < IN / 4; ++q) {
                const float4 v = xd4[q];
                acc = fmaf(w[4*q+0], v.x, acc); acc = fmaf(w[4*q+1], v.y, acc);
                acc = fmaf(w[4*q+2], v.z, acc); acc = fmaf(w[4*q+3], v.w, acc);
            }
            #pragma unroll
            for (int q = 0; q < IN / 4; ++q) {
                const float4 v = xs4[q];
                acc = fmaf(w[IN+4*q+0], v.x, acc); acc = fmaf(w[IN+4*q+1], v.y, acc);
                acc = fmaf(w[IN+4*q+2], v.z, acc); acc = fmaf(w[IN+4*q+3], v.w, acc);
            }
        } else {
            const float* __restrict__ xd = &x[(long)dst * IN];
            const float* __restrict__ xs = &x[(long)src * IN];
            #pragma unroll
            for (int j = 0; j < IN; ++j) acc = fmaf(w[j], xd[j], acc);
            #pragma unroll
            for (int j = 0; j < IN; ++j) acc = fmaf(w[IN + j], xs[j], acc);
        }
        const float* __restrict__ eav = &ea[(long)e * EA];
        #pragma unroll
        for (int j = 0; j < EA; ++j) acc = fmaf(w[2 * IN + j], eav[j], acc);
        acc = acc > 0.f ? acc : 0.01f * acc;     // leaky_relu(0.01)
        atomicAdd(&out[(long)dst * OUT + c], acc);
    }
}

// ---------------- spatial edge layer as fused gather-MFMA-scatter GEMM -----
template<int IN, int EA, int OUT, int KSTEPS>
__global__ __launch_bounds__(256)
void spatial_gemm_kernel(const float* __restrict__ x,
                         const int* __restrict__ ei, int E,
                         const float* __restrict__ ea,
                         const float* __restrict__ Wl,
                         const float* __restrict__ bl,
                         float* __restrict__ out)
{
    constexpr int Z    = 2 * IN + EA;
    constexpr int KPAD = KSTEPS * 32;
    static_assert(Z <= KPAD, "K pad");
    static_assert(IN % 8 == 0, "IN vec");
    constexpr int LDA = KPAD + 8;      // multiple of 8 ushorts (16B aligned rows)
    constexpr int MT  = 128;
    constexpr int NF  = OUT / 16;
    __shared__ ushort sA[MT * LDA];
    __shared__ ushort sB[OUT * LDA];
    __shared__ float  sBias[OUT];
    __shared__ int    sDst[MT];

    const int tid = threadIdx.x;
    const int e0  = blockIdx.x * MT;

    // stage B (zero-padded k)
    for (int i = tid; i < OUT * KPAD; i += 256) {
        const int ch = i / KPAD, j = i % KPAD;
        sB[ch * LDA + j] = (j < Z) ? f2bf(Wl[ch * Z + j]) : (ushort)0;
    }
    if (tid < OUT) sBias[tid] = bl[tid];

    // stage A: 2 threads per edge row (sh=0: dst half, sh=1: src half + ea + pad)
    {
        const int r  = tid >> 1, sh = tid & 1;
        const int e  = e0 + r;
        const int node = sh ? ei[e] : ei[E + e];
        const float4* __restrict__ xr = (const float4*)&x[(long)node * IN];
        ushort* d = &sA[r * LDA + sh * IN];
        #pragma unroll
        for (int q = 0; q < IN / 4; q += 2)
            pack8(d + q * 4, xr[q], xr[q + 1]);
        if (sh == 0) {
            sDst[r] = node;
        } else {
            const float* __restrict__ eav = &ea[(long)e * EA];
            #pragma unroll
            for (int j = 0; j < EA; ++j) d[IN + j] = f2bf(eav[j]);  // abs 2*IN+j
            #pragma unroll
            for (int j = Z; j < KPAD; ++j) sA[r * LDA + j] = 0;
        }
    }
    __syncthreads();

    const int lane = tid & 63, wid = tid >> 6;
    const int g = lane >> 4, rsel = lane & 15;
    f32x4 acc[2][NF] = {};
    #pragma unroll
    for (int ks = 0; ks < KSTEPS; ++ks) {
        bf16x8 a_[2], b_[NF];
        #pragma unroll
        for (int m = 0; m < 2; ++m)
            a_[m] = *(const bf16x8*)&sA[(wid*32 + m*16 + rsel) * LDA + ks*32 + g*8];
        #pragma unroll
        for (int n = 0; n < NF; ++n)
            b_[n] = *(const bf16x8*)&sB[(n*16 + rsel) * LDA + ks*32 + g*8];
        #pragma unroll
        for (int m = 0; m < 2; ++m)
            #pragma unroll
            for (int n = 0; n < NF; ++n)
                acc[m][n] = __builtin_amdgcn_mfma_f32_16x16x32_bf16(
                    a_[m], b_[n], acc[m][n], 0, 0, 0);
    }

    // epilogue: row = wid*32 + m*16 + g*4 + rr ; col = n*16 + rsel
    #pragma unroll
    for (int m = 0; m < 2; ++m) {
        #pragma unroll
        for (int rr = 0; rr < 4; ++rr) {
            const int row = wid*32 + m*16 + g*4 + rr;
            const long dst = sDst[row];
            #pragma unroll
            for (int n = 0; n < NF; ++n) {
                const int col = n*16 + rsel;
                float v = acc[m][n][rr] + sBias[col];
                v = v > 0.f ? v : 0.01f * v;
                atomicAdd(&out[dst * OUT + col], v);
            }
        }
    }
}

// ---------------- generic upsample (residual linear) -----------------------
template<int IN, int OUT, int ITER>
__global__ __launch_bounds__(256)
void upsample_kernel(const float* __restrict__ x, int N,
                     const float* __restrict__ Wu,
                     const float* __restrict__ bu,
                     float* __restrict__ out)
{
    constexpr int INp = (IN % 2 == 0) ? IN + 1 : IN;
    __shared__ float sW[OUT * INp];
    __shared__ float sB[OUT];
    for (int i = threadIdx.x; i < OUT * IN; i += 256)
        sW[(i / IN) * INp + (i % IN)] = Wu[i];
    for (int i = threadIdx.x; i < OUT; i += 256) sB[i] = bu[i];
    __syncthreads();

    const int total = N * OUT;
    #pragma unroll 1
    for (int it = 0; it < ITER; ++it) {
        const int idx = (blockIdx.x * ITER + it) * 256 + threadIdx.x;
        if (idx >= total) break;
        const int n = idx / OUT, c = idx % OUT;
        const float* __restrict__ w = &sW[c * INp];
        float acc = sB[c];
        if constexpr (IN % 4 == 0) {
            const float4* __restrict__ xv4 = (const float4*)&x[(long)n * IN];
            #pragma unroll
            for (int q = 0; q < IN / 4; ++q) {
                const float4 v = xv4[q];
                acc = fmaf(w[4*q+0], v.x, acc); acc = fmaf(w[4*q+1], v.y, acc);
                acc = fmaf(w[4*q+2], v.z, acc); acc = fmaf(w[4*q+3], v.w, acc);
            }
        } else {
            const float* __restrict__ xv = &x[(long)n * IN];
            #pragma unroll
            for (int j = 0; j < IN; ++j) acc = fmaf(w[j], xv[j], acc);
        }
        out[idx] = acc;
    }
}

template<int ITER>
__global__ __launch_bounds__(256)
void dec1_upsample_kernel(const __hip_bfloat16* __restrict__ zt,
                          const float* __restrict__ lo,
                          const float* __restrict__ up,
                          const float* __restrict__ Wu,  // [32, 66]
                          const float* __restrict__ bu,
                          float* __restrict__ out, int N)
{
    constexpr int IN = 66, INp = 67, OUT = 32;
    __shared__ float sW[OUT * INp];
    __shared__ float sB[OUT];
    for (int i = threadIdx.x; i < OUT * IN; i += 256)
        sW[(i / IN) * INp + (i % IN)] = Wu[i];
    if (threadIdx.x < OUT) sB[threadIdx.x] = bu[threadIdx.x];
    __syncthreads();

    const int total = N * OUT;
    #pragma unroll 1
    for (int it = 0; it < ITER; ++it) {
        const int idx = (blockIdx.x * ITER + it) * 256 + threadIdx.x;
        if (idx >= total) break;
        const int n = idx >> 5, c = idx & 31;
        const float* __restrict__ w = &sW[c * INp];
        const uint4* __restrict__ zn4 = (const uint4*)&zt[(long)n * 64];
        float acc = sB[c];
        #pragma unroll
        for (int q = 0; q < 8; ++q) {
            const uint4 u = zn4[q];
            float2 v;
            v = bf2_unpack(u.x); acc = fmaf(w[8*q+0], v.x, acc); acc = fmaf(w[8*q+1], v.y, acc);
            v = bf2_unpack(u.y); acc = fmaf(w[8*q+2], v.x, acc); acc = fmaf(w[8*q+3], v.y, acc);
            v = bf2_unpack(u.z); acc = fmaf(w[8*q+4], v.x, acc); acc = fmaf(w[8*q+5], v.y, acc);
            v = bf2_unpack(u.w); acc = fmaf(w[8*q+6], v.x, acc); acc = fmaf(w[8*q+7], v.y, acc);
        }
        acc = fmaf(w[64], lo[n], acc);
        acc = fmaf(w[65], up[n], acc);
        out[idx] = acc;
    }
}

// ---------------- temporal (dim 64) as fused gather-MFMA-scatter GEMM ------
__global__ __launch_bounds__(256)
void temporal_gemm_kernel(const float* __restrict__ x,
                          const int* __restrict__ ei, int E,
                          const float* __restrict__ Wt,  // [64,128]
                          const float* __restrict__ bt,
                          float* __restrict__ s, float* __restrict__ cnt)
{
    constexpr int MT = 128, LDA = 136, LDB = 136;
    __shared__ ushort sA[MT * LDA];     // 34816 B
    __shared__ ushort sB[64 * LDB];     // 17408 B
    __shared__ float  sBias[64];
    __shared__ int    sDst[MT];

    const int tid = threadIdx.x;
    const int e0  = blockIdx.x * MT;

    // stage B (Wt) + bias
    for (int i = tid; i < 64 * 32; i += 256) {
        const int ch = i >> 5, q = i & 31;
        const float4 v = *(const float4*)&Wt[ch * 128 + q * 4];
        ushort* d = &sB[ch * LDB + q * 4];
        d[0] = f2bf(v.x); d[1] = f2bf(v.y); d[2] = f2bf(v.z); d[3] = f2bf(v.w);
    }
    if (tid < 64) sBias[tid] = bt[tid];

    // stage A: 2 threads per edge row (sh=0: dst half, sh=1: src half)
    {
        const int r  = tid >> 1, sh = tid & 1;
        const int e  = e0 + r;
        const int node = sh ? ei[e] : ei[E + e];
        const float4* __restrict__ xr = (const float4*)&x[(long)node * 64];
        ushort* d = &sA[r * LDA + sh * 64];
        #pragma unroll
        for (int q = 0; q < 16; q += 2)
            pack8(d + q * 4, xr[q], xr[q + 1]);
        if (sh == 0) {
            sDst[r] = node;
            atomicAdd(&cnt[node], 1.f);
        }
    }
    __syncthreads();

    // MFMA: wave wid owns edge rows [wid*32, wid*32+32)
    const int lane = tid & 63, wid = tid >> 6;
    const int g = lane >> 4, rsel = lane & 15;
    f32x4 acc[2][4] = {};
    #pragma unroll
    for (int ks = 0; ks < 4; ++ks) {
        bf16x8 a_[2], b_[4];
        #pragma unroll
        for (int m = 0; m < 2; ++m)
            a_[m] = *(const bf16x8*)&sA[(wid*32 + m*16 + rsel) * LDA + ks*32 + g*8];
        #pragma unroll
        for (int n = 0; n < 4; ++n)
            b_[n] = *(const bf16x8*)&sB[(n*16 + rsel) * LDB + ks*32 + g*8];
        #pragma unroll
        for (int m = 0; m < 2; ++m)
            #pragma unroll
            for (int n = 0; n < 4; ++n)
                acc[m][n] = __builtin_amdgcn_mfma_f32_16x16x32_bf16(
                    a_[m], b_[n], acc[m][n], 0, 0, 0);
    }

    #pragma unroll
    for (int m = 0; m < 2; ++m) {
        #pragma unroll
        for (int rr = 0; rr < 4; ++rr) {
            const int row = wid*32 + m*16 + g*4 + rr;
            const long dst = sDst[row];
            #pragma unroll
            for (int n = 0; n < 4; ++n) {
                const int col = n*16 + rsel;
                const float v = fmaxf(acc[m][n][rr] + sBias[col], 0.f);
                atomicAdd(&s[dst * 64 + col], v);
            }
        }
    }
}

// ---------------- decoder layer-1 as fused gather-MFMA-scatter GEMM --------
__global__ __launch_bounds__(256)
void dec1_gemm_kernel(const __hip_bfloat16* __restrict__ zt,
                      const float* __restrict__ lo, const float* __restrict__ up,
                      const int* __restrict__ ei, int E,
                      const float* __restrict__ ea,   // [E,6]
                      const float* __restrict__ Wl,   // [32,138]
                      const float* __restrict__ bl,
                      float* __restrict__ out)        // [N2,32]
{
    constexpr int MT = 128, LDA = 168, LDB = 168;
    __shared__ ushort sA[MT * LDA];     // 43008 B
    __shared__ ushort sB[32 * LDB];     // 10752 B
    __shared__ float  sBias[32];
    __shared__ int    sDst[MT];

    const int tid = threadIdx.x;
    const int e0  = blockIdx.x * MT;

    for (int i = tid; i < 32 * 160; i += 256) {
        const int ch = i / 160, j = i % 160;
        sB[ch * LDB + j] = (j < 138) ? f2bf(Wl[ch * 138 + j]) : (ushort)0;
    }
    if (tid < 32) sBias[tid] = bl[tid];

    {
        const int r  = tid >> 1, sh = tid & 1;
        const int e  = e0 + r;
        const int node = sh ? ei[e] : ei[E + e];
        ushort* d = &sA[r * LDA + sh * 66];
        uint* d32 = (uint*)d;                     // 4B-aligned
        const uint4* __restrict__ zr = (const uint4*)&zt[(long)node * 64];
        #pragma unroll
        for (int q = 0; q < 8; ++q) {
            const uint4 u = zr[q];
            d32[4*q+0] = u.x; d32[4*q+1] = u.y; d32[4*q+2] = u.z; d32[4*q+3] = u.w;
        }
        d[64] = f2bf(lo[node]);
        d[65] = f2bf(up[node]);
        if (sh) {
            const float* __restrict__ eav = &ea[(long)e * 6];
            #pragma unroll
            for (int j = 0; j < 6; ++j) d[66 + j] = f2bf(eav[j]);
            #pragma unroll
            for (int j = 72; j < 94; ++j) d[j] = 0;   // k 138..159
        } else {
            sDst[r] = node;
        }
    }
    __syncthreads();

    const int lane = tid & 63, wid = tid >> 6;
    const int g = lane >> 4, rsel = lane & 15;
    f32x4 acc[2][2] = {};
    #pragma unroll
    for (int ks = 0; ks < 5; ++ks) {
        bf16x8 a_[2], b_[2];
        #pragma unroll
        for (int m = 0; m < 2; ++m)
            a_[m] = *(const bf16x8*)&sA[(wid*32 + m*16 + rsel) * LDA + ks*32 + g*8];
        #pragma unroll
        for (int n = 0; n < 2; ++n)
            b_[n] = *(const bf16x8*)&sB[(n*16 + rsel) * LDB + ks*32 + g*8];
        #pragma unroll
        for (int m = 0; m < 2; ++m)
            #pragma unroll
            for (int n = 0; n < 2; ++n)
                acc[m][n] = __builtin_amdgcn_mfma_f32_16x16x32_bf16(
                    a_[m], b_[n], acc[m][n], 0, 0, 0);
    }

    #pragma unroll
    for (int m = 0; m < 2; ++m) {
        #pragma unroll
        for (int rr = 0; rr < 4; ++rr) {
            const int row = wid*32 + m*16 + g*4 + rr;
            const long dst = sDst[row];
            #pragma unroll
            for (int n = 0; n < 2; ++n) {
                const int col = n*16 + rsel;
                float v = acc[m][n][rr] + sBias[col];
                v = v > 0.f ? v : 0.01f * v;
                atomicAdd(&out[dst * 32 + col], v);
            }
        }
    }
}

// ---------------- temporal combine / dim-1 temporal ------------------------
__global__ void temporal_combine64_kernel(const float* __restrict__ s,
                                          const float* __restrict__ cnt,
                                          const float* __restrict__ x,
                                          float* __restrict__ z, int N)
{
    int idx = blockIdx.x * blockDim.x + threadIdx.x;
    if (idx >= N * 64) return;
    const int n = idx >> 6;
    z[idx] = s[idx] / fmaxf(cnt[n], 1.f) + x[idx];
}

__global__ void temporal_edge1_kernel(const float* __restrict__ x,
                                      const int* __restrict__ ei, int E,
                                      const float* __restrict__ Wt,
                                      const float* __restrict__ bt,
                                      float* __restrict__ s, float* __restrict__ cnt)
{
    int e = blockIdx.x * blockDim.x + threadIdx.x;
    if (e >= E) return;
    const int src = ei[e];
    const int dst = ei[E + e];
    float m = Wt[0] * x[dst] + Wt[1] * x[src] + bt[0];
    m = fmaxf(m, 0.f);
    atomicAdd(&s[dst], m);
    atomicAdd(&cnt[dst], 1.f);
}

// ---------------- transform GEMM (bf16 MFMA, swizzled, coalesced) ----------
__global__ __launch_bounds__(256)
void gemm_mfma_tanh_kernel(const float* __restrict__ A,
                           const float* __restrict__ W,
                           const float* __restrict__ bias,
                           __hip_bfloat16* __restrict__ out)
{
    constexpr int BM = 128, LDP = 40;   // ushort pitch: 80B rows, 2-way banks
    constexpr int LDC = 152;            // epilogue staging pitch (304B rows)
    __shared__ __align__(16) ushort smem[2 * BM * LDP];   // 20480 B
    ushort* sA = smem;
    ushort* sB = smem + BM * LDP;
    const int tid  = threadIdx.x;
    const int lane = tid & 63;
    const int wid  = tid >> 6;
    const int wr = wid >> 1, wc = wid & 1;

    // XCD-chunked swizzle: round-robin dispatch -> contiguous chunks per XCD,
    // so the kN/128=7 blocks sharing an A-panel hit the same XCD L2.
    const int nwg = gridDim.x;            // 3584 (divisible by 8)
    const int cpx = nwg >> 3;
    const int bid = blockIdx.x;
    const int swz = (bid & 7) * cpx + (bid >> 3);
    const long bm = (long)(swz / (kN / BM)) * BM;
    const long bn = (long)(swz % (kN / BM)) * BM;

    const int sr = tid >> 1;      // 0..127: staged tile row
    const int sh = tid & 1;       // 0/1: which 16-element k-half
    const float* __restrict__ gA = &A[(bm + sr) * kK + sh * 16];
    const float* __restrict__ gB = &W[(bn + sr) * kK + sh * 16];
    ushort* dA = &sA[sr * LDP + sh * 16];
    ushort* dB = &sB[sr * LDP + sh * 16];

    f32x4 acc[4][4] = {};
    const int g    = lane >> 4;   // k-group (8 bf16 each)
    const int rsel = lane & 15;

    for (int k0 = 0; k0 < kK; k0 += 32) {
        const float4 a0 = *(const float4*)(gA + k0 + 0);
        const float4 a1 = *(const float4*)(gA + k0 + 4);
        const float4 a2 = *(const float4*)(gA + k0 + 8);
        const float4 a3 = *(const float4*)(gA + k0 + 12);
        const float4 b0 = *(const float4*)(gB + k0 + 0);
        const float4 b1 = *(const float4*)(gB + k0 + 4);
        const float4 b2 = *(const float4*)(gB + k0 + 8);
        const float4 b3 = *(const float4*)(gB + k0 + 12);
        __syncthreads();                      // previous tile fully consumed
        pack8(dA, a0, a1); pack8(dA + 8, a2, a3);
        pack8(dB, b0, b1); pack8(dB + 8, b2, b3);
        __syncthreads();

        bf16x8 af[4], bfm[4];
        #pragma unroll
        for (int m = 0; m < 4; ++m)
            af[m] = *(const bf16x8*)&sA[(wr * 64 + m * 16 + rsel) * LDP + g * 8];
        #pragma unroll
        for (int n = 0; n < 4; ++n)
            bfm[n] = *(const bf16x8*)&sB[(wc * 64 + n * 16 + rsel) * LDP + g * 8];
        #pragma unroll
        for (int m = 0; m < 4; ++m)
            #pragma unroll
            for (int n = 0; n < 4; ++n)
                acc[m][n] = __builtin_amdgcn_mfma_f32_16x16x32_bf16(
                    af[m], bfm[n], acc[m][n], 0, 0, 0);
    }

    // bias per lane-owned columns
    float bias_r[4];
    #pragma unroll
    for (int n = 0; n < 4; ++n)
        bias_r[n] = bias[bn + wc * 64 + n * 16 + rsel];

    // Coalesced epilogue: two passes of 64 rows via LDS staging (reuses smem).
    ushort* sC = smem;
    __syncthreads();
    #pragma unroll
    for (int p = 0; p < 2; ++p) {
        if (wr == p) {
            #pragma unroll
            for (int m = 0; m < 4; ++m)
                #pragma unroll
                for (int n = 0; n < 4; ++n)
                    #pragma unroll
                    for (int r = 0; r < 4; ++r) {
                        const int row = m * 16 + g * 4 + r;
                        const int col = wc * 64 + n * 16 + rsel;
                        sC[row * LDC + col] = f2bf(tanhf(acc[m][n][r] + bias_r[n]));
                    }
        }
        __syncthreads();
        {
            const int row = tid >> 2, ch = tid & 3;     // 64 rows x 4 chunks of 64B
            const uint4* __restrict__ srcp = (const uint4*)&sC[row * LDC + ch * 32];
            uint4* __restrict__ dstp = (uint4*)&out[(bm + p * 64 + row) * kN + bn + ch * 32];
            #pragma unroll
            for (int q = 0; q < 4; ++q) dstp[q] = srcp[q];
        }
        __syncthreads();
    }
}

// ---------------- final: tanh(temporal) -> affine to joint range -----------
__global__ void final_kernel(const float* __restrict__ s,
                             const float* __restrict__ cnt,
                             const float* __restrict__ d3,
                             const float* __restrict__ lo,
                             const float* __restrict__ up,
                             float* __restrict__ out, int N)
{
    int i = blockIdx.x * blockDim.x + threadIdx.x;
    if (i >= N) return;
    const float t = s[i] / fmaxf(cnt[i], 1.f) + d3[i];
    const float o = tanhf(t);
    out[i] = lo[i] + (up[i] - lo[i]) * (o + 1.f) * 0.5f;
}

// ---------------------------------------------------------------------------
extern "C" void kernel_launch(void* const* d_in, const int* in_sizes, int n_in,
                              void* d_out, int out_size, void* d_ws, size_t ws_size,
                              hipStream_t stream)
{
    const float* x     = (const float*)d_in[0];
    const int*   ei1   = (const int*)  d_in[1];
    const float* ea1   = (const float*)d_in[2];
    const int*   tei1  = (const int*)  d_in[3];
    const float* lower = (const float*)d_in[4];
    const float* upper = (const float*)d_in[5];
    const int*   ei2   = (const int*)  d_in[6];
    const float* ea2   = (const float*)d_in[7];
    const int*   tei2  = (const int*)  d_in[8];
    const float* We1_l = (const float*)d_in[9];  const float* be1_l = (const float*)d_in[10];
    const float* We1_u = (const float*)d_in[11]; const float* be1_u = (const float*)d_in[12];
    const float* We2_l = (const float*)d_in[13]; const float* be2_l = (const float*)d_in[14];
    const float* We2_u = (const float*)d_in[15]; const float* be2_u = (const float*)d_in[16];
    const float* We3_l = (const float*)d_in[17]; const float* be3_l = (const float*)d_in[18];
    const float* We3_u = (const float*)d_in[19]; const float* be3_u = (const float*)d_in[20];
    const float* Wt1   = (const float*)d_in[21]; const float* bt1   = (const float*)d_in[22];
    const float* W_tr  = (const float*)d_in[23]; const float* b_tr  = (const float*)d_in[24];
    const float* Wd1_l = (const float*)d_in[25]; const float* bd1_l = (const float*)d_in[26];
    const float* Wd1_u = (const float*)d_in[27]; const float* bd1_u = (const float*)d_in[28];
    const float* Wd2_l = (const float*)d_in[29]; const float* bd2_l = (const float*)d_in[30];
    const float* Wd2_u = (const float*)d_in[31]; const float* bd2_u = (const float*)d_in[32];
    const float* Wd3_l = (const float*)d_in[33]; const float* bd3_l = (const float*)d_in[34];
    const float* Wd3_u = (const float*)d_in[35]; const float* bd3_u = (const float*)d_in[36];
    const float* Wt2   = (const float*)d_in[37]; const float* bt2   = (const float*)d_in[38];

    // workspace layout (bytes):
    //   bufA: 117,440,512   (holds h1/h3/zt(bf16)/d2)
    //   bufB: 117,440,512   (holds h2/s1/z/d1/d3)
    //   bufC:   7,340,032   (holds cnt1 | s2+cnt2)
    char* ws = (char*)d_ws;
    float* bufA = (float*)ws;
    float* bufB = (float*)(ws + 117440512);
    float* bufC = (float*)(ws + 234881024);
    __hip_bfloat16* zt = (__hip_bfloat16*)bufA;

    const int TPB = 256;
    auto cdiv = [](long a, long b) { return (int)((a + b - 1) / b); };

    // ---- encoder spatial 1: x[6] -> h1[16]  (h1 = bufA)
    upsample_kernel<6, 16, 8><<<cdiv((long)kN1 * 16, 2048), TPB, 0, stream>>>(
        x, kN1, We1_u, be1_u, bufA);
    spatial_edge_kernel<6, 3, 16, 256, 4><<<cdiv(kE1, 64), TPB, 0, stream>>>(
        x, ei1, kE1, ea1, We1_l, be1_l, bufA);

    // ---- encoder spatial 2: h1[16] -> h2[32]  (h2 = bufB)
    upsample_kernel<16, 32, 8><<<cdiv((long)kN1 * 32, 2048), TPB, 0, stream>>>(
        bufA, kN1, We2_u, be2_u, bufB);
    spatial_gemm_kernel<16, 3, 32, 2><<<kE1 / 128, TPB, 0, stream>>>(
        bufA, ei1, kE1, ea1, We2_l, be2_l, bufB);

    // ---- encoder spatial 3: h2[32] -> h3[64]  (h3 = bufA)
    upsample_kernel<32, 64, 8><<<cdiv((long)kN1 * 64, 2048), TPB, 0, stream>>>(
        bufB, kN1, We3_u, be3_u, bufA);
    spatial_gemm_kernel<32, 3, 64, 3><<<kE1 / 128, TPB, 0, stream>>>(
        bufB, ei1, kE1, ea1, We3_l, be3_l, bufA);

    // ---- encoder temporal (dim 64): s1 = bufB, cnt1 = bufC, z in-place bufB
    hipMemsetAsync(bufB, 0, (size_t)kN1 * 64 * sizeof(float), stream);
    hipMemsetAsync(bufC, 0, (size_t)kN1 * sizeof(float), stream);
    temporal_gemm_kernel<<<kN1 / 128, 256, 0, stream>>>(
        bufA, tei1, kN1, Wt1, bt1, bufB, bufC);
    temporal_combine64_kernel<<<cdiv((long)kN1 * 64, TPB), TPB, 0, stream>>>(
        bufB, bufC, bufA, bufB, kN1);

    // ---- transform GEMM: z(bufB [65536,384] f32) @ W_tr^T -> tanh -> zt bf16
    gemm_mfma_tanh_kernel<<<(kN / 128) * (kM / 128), 256, 0, stream>>>(
        bufB, W_tr, b_tr, zt);

    // ---- decoder spatial 1: x2[66] (virtual) -> d1[32]  (d1 = bufB)
    dec1_upsample_kernel<8><<<cdiv((long)kN2 * 32, 2048), TPB, 0, stream>>>(
        zt, lower, upper, Wd1_u, bd1_u, bufB, kN2);
    dec1_gemm_kernel<<<kE2 / 128, 256, 0, stream>>>(
        zt, lower, upper, ei2, kE2, ea2, Wd1_l, bd1_l, bufB);

    // ---- decoder spatial 2: d1[32] -> d2[16]  (d2 = bufA as f32)
    float* d2 = (float*)bufA;
    upsample_kernel<32, 16, 8><<<cdiv((long)kN2 * 16, 2048), TPB, 0, stream>>>(
        bufB, kN2, Wd2_u, bd2_u, d2);
    spatial_gemm_kernel<32, 6, 16, 3><<<kE2 / 128, TPB, 0, stream>>>(
        bufB, ei2, kE2, ea2, Wd2_l, bd2_l, d2);

    // ---- decoder spatial 3: d2[16] -> d3[1]  (d3 = bufB)
    float* d3 = bufB;
    upsample_kernel<16, 1, 8><<<cdiv(kN2, 2048), TPB, 0, stream>>>(
        d2, kN2, Wd3_u, bd3_u, d3);
    spatial_edge_kernel<16, 6, 1, 256, 1><<<cdiv(kE2, 256), TPB, 0, stream>>>(
        d2, ei2, kE2, ea2, Wd3_l, bd3_l, d3);

    // ---- decoder temporal (dim 1) + final affine
    hipMemsetAsync(bufC, 0, (size_t)2 * kN2 * sizeof(float), stream);
    temporal_edge1_kernel<<<cdiv(kN2, TPB), TPB, 0, stream>>>(
        d3, tei2, kN2, Wt2, bt2, bufC, bufC + kN2);
    final_kernel<<<cdiv(kN2, TPB), TPB, 0, stream>>>(
        bufC, bufC + kN2, d3, lower, upper, (float*)d_out, kN2);
}